// Round 4
// baseline (492.732 us; speedup 1.0000x reference)
//
#include <hip/hip_runtime.h>
#include <hip/hip_bf16.h>

// ============================================================================
// DIAGNOSTIC ROUND: each kernel body repeated REP_* times (identical writes,
// deterministic) so per-dispatch durations exceed the 43us fillBuffer floor
// and appear in the rocprof top-5. True per-kernel time = dur_us / REP_*.
// ============================================================================
#define REP_TOBF 16
#define REP_GEMM 8
#define REP_DOTS 32
#define REP_ATTN 8

// Problem constants (from reference)
#define Hd   768
#define Bsz  4
#define Ent  42
#define Mm   16
#define NEGV (-1e9f)

#define GM 2688          // B*E*M rows
#define GN 1536          // concat(head, tail) outputs
#define GK 768
#define NT (GK / 32)     // 24 K-steps

typedef short bf16x8 __attribute__((ext_vector_type(8)));
typedef float f32x4  __attribute__((ext_vector_type(4)));
typedef unsigned short u16x8 __attribute__((ext_vector_type(8)));

static __device__ __forceinline__ unsigned short f2bf(float x) {
    unsigned int u = __float_as_uint(x);
    u += 0x7fffu + ((u >> 16) & 1u);          // RNE
    return (unsigned short)(u >> 16);
}
static __device__ __forceinline__ float bf2f(unsigned short v) {
    return __uint_as_float(((unsigned int)v) << 16);
}

// ---------------------------------------------------------------------------
// Kernel 0: fp32 -> bf16 conversion.
// ---------------------------------------------------------------------------
__global__ __launch_bounds__(256)
void to_bf16(const float* __restrict__ me, const float* __restrict__ wh,
             const float* __restrict__ wt, unsigned short* __restrict__ dst)
{
    for (int rep = 0; rep < REP_TOBF; ++rep) {
        asm volatile("" ::: "memory");
        const int t = blockIdx.x * 256 + threadIdx.x;
        const size_t e = (size_t)t * 8;
        const size_t row = e / Hd;
        const float* src;
        size_t off;
        if (row < 2688)      { src = me; off = e; }
        else if (row < 3456) { src = wh; off = e - (size_t)2688 * Hd; }
        else                 { src = wt; off = e - (size_t)3456 * Hd; }
        float4 v0 = *reinterpret_cast<const float4*>(src + off);
        float4 v1 = *reinterpret_cast<const float4*>(src + off + 4);
        u16x8 o;
        o[0] = f2bf(v0.x); o[1] = f2bf(v0.y); o[2] = f2bf(v0.z); o[3] = f2bf(v0.w);
        o[4] = f2bf(v1.x); o[5] = f2bf(v1.y); o[6] = f2bf(v1.z); o[7] = f2bf(v1.w);
        *reinterpret_cast<u16x8*>(dst + e) = o;
    }
}

// ---------------------------------------------------------------------------
// Kernel 1: bf16 MFMA GEMM + ReLU (identical structure to round 3).
// ---------------------------------------------------------------------------
__global__ __launch_bounds__(256)
void gemm_mfma(const unsigned short* __restrict__ Ab,
               const unsigned short* __restrict__ Wb,
               unsigned short* __restrict__ f_head,
               unsigned short* __restrict__ f_tail)
{
    __shared__ unsigned short As[2][128 * 32];
    __shared__ unsigned short Bs[2][128 * 32];

    const int tid  = threadIdx.x;
    const int wave = tid >> 6;
    const int lane = tid & 63;
    const int n0 = blockIdx.x * 128;
    const int m0 = blockIdx.y * 128;
    const int wr = wave >> 1;
    const int wc = wave & 1;

    const int srow = wave * 16 + (lane >> 2);
    const int scol = (lane & 3) * 8;
    const unsigned short* Aga = Ab + (size_t)(m0 + srow) * GK + scol;
    const unsigned short* Bga = Wb + (size_t)(n0 + srow) * GK + scol;

#define STAGE(buf, k0) do { \
    __builtin_amdgcn_global_load_lds((const __attribute__((address_space(1))) void*)(Aga + (k0)), \
        (__attribute__((address_space(3))) void*)(As[buf] + wave * 512), 16, 0, 0); \
    __builtin_amdgcn_global_load_lds((const __attribute__((address_space(1))) void*)(Aga + 64 * GK + (k0)), \
        (__attribute__((address_space(3))) void*)(As[buf] + 2048 + wave * 512), 16, 0, 0); \
    __builtin_amdgcn_global_load_lds((const __attribute__((address_space(1))) void*)(Bga + (k0)), \
        (__attribute__((address_space(3))) void*)(Bs[buf] + wave * 512), 16, 0, 0); \
    __builtin_amdgcn_global_load_lds((const __attribute__((address_space(1))) void*)(Bga + 64 * GK + (k0)), \
        (__attribute__((address_space(3))) void*)(Bs[buf] + 2048 + wave * 512), 16, 0, 0); \
} while (0)

    const int frow = lane & 15;
    const int koff = (lane >> 4) * 8;

    for (int rep = 0; rep < REP_GEMM; ++rep) {
        asm volatile("" ::: "memory");
        f32x4 acc[4][4];
        {
            f32x4 z = {0.f, 0.f, 0.f, 0.f};
            #pragma unroll
            for (int mi = 0; mi < 4; ++mi)
                #pragma unroll
                for (int ni = 0; ni < 4; ++ni) acc[mi][ni] = z;
        }

        STAGE(0, 0);
        int cur = 0;
        #pragma unroll 1
        for (int t = 0; t < NT; ++t) {
            __syncthreads();
            if (t < NT - 1) STAGE(cur ^ 1, (t + 1) * 32);
            const unsigned short* ap = As[cur] + (wr * 64 + frow) * 32 + koff;
            const unsigned short* bp = Bs[cur] + (wc * 64 + frow) * 32 + koff;
            bf16x8 a[4], b[4];
            #pragma unroll
            for (int mi = 0; mi < 4; ++mi)
                a[mi] = *reinterpret_cast<const bf16x8*>(ap + mi * 16 * 32);
            #pragma unroll
            for (int ni = 0; ni < 4; ++ni)
                b[ni] = *reinterpret_cast<const bf16x8*>(bp + ni * 16 * 32);
            #pragma unroll
            for (int mi = 0; mi < 4; ++mi)
                #pragma unroll
                for (int ni = 0; ni < 4; ++ni)
                    acc[mi][ni] = __builtin_amdgcn_mfma_f32_16x16x32_bf16(a[mi], b[ni], acc[mi][ni], 0, 0, 0);
            cur ^= 1;
        }

        const bool isHead = (n0 < Hd);
        unsigned short* outp = isHead ? f_head : f_tail;
        const int nbase = (isHead ? n0 : (n0 - Hd)) + wc * 64 + frow;
        const int rbase = m0 + wr * 64 + (lane >> 4) * 4;
        #pragma unroll
        for (int mi = 0; mi < 4; ++mi)
            #pragma unroll
            for (int ni = 0; ni < 4; ++ni)
                #pragma unroll
                for (int j = 0; j < 4; ++j) {
                    float v = fmaxf(acc[mi][ni][j], 0.f);
                    outp[(size_t)(rbase + mi * 16 + j) * Hd + nbase + ni * 16] = f2bf(v);
                }
        __syncthreads();   // all LDS reads of this rep done before next rep STAGEs
    }
#undef STAGE
}

// ---------------------------------------------------------------------------
// Kernel 2: per-row dots.
// ---------------------------------------------------------------------------
__global__ __launch_bounds__(256)
void row_dots(const unsigned short* __restrict__ f_head,
              const unsigned short* __restrict__ f_tail,
              const float* __restrict__ w_c, const float* __restrict__ w_q,
              const float* __restrict__ w_cq,
              float* __restrict__ ch, float* __restrict__ qt, float* __restrict__ cqt)
{
    for (int rep = 0; rep < REP_DOTS; ++rep) {
        asm volatile("" ::: "memory");
        const int wave = threadIdx.x >> 6;
        const int lane = threadIdx.x & 63;
        const int r = blockIdx.x * 4 + wave;
        const unsigned short* fh = f_head + (size_t)r * Hd;
        const unsigned short* ft = f_tail + (size_t)r * Hd;
        float pc = 0.f, pq = 0.f, pcq = 0.f;
        #pragma unroll
        for (int j = 0; j < Hd / 64; ++j) {
            const int c = j * 64 + lane;
            float vh = bf2f(fh[c]), vt = bf2f(ft[c]);
            pc += vh * w_c[c]; pq += vt * w_q[c]; pcq += vt * w_cq[c];
        }
        #pragma unroll
        for (int s = 32; s >= 1; s >>= 1) {
            pc  += __shfl_down(pc, s);
            pq  += __shfl_down(pq, s);
            pcq += __shfl_down(pcq, s);
        }
        if (lane == 0) { ch[r] = pc; qt[r] = pq; cqt[r] = pcq; }
    }
}

// ---------------------------------------------------------------------------
// Kernel 3: per-pair attention (identical structure to round 3).
// ---------------------------------------------------------------------------
__global__ __launch_bounds__(256)
void pair_attn(const unsigned short* __restrict__ f_head,
               const unsigned short* __restrict__ f_tail,
               const float* __restrict__ ch, const float* __restrict__ qt,
               const float* __restrict__ cqt,
               const float* __restrict__ entity_embed,
               const int* __restrict__ mention_num,
               const int* __restrict__ b_ind, const int* __restrict__ h_ind,
               const int* __restrict__ t_ind,
               float* __restrict__ out, int N)
{
    __shared__ float sm[Mm][Mm];
    __shared__ float hw[Mm], tw[Mm];

    for (int rep = 0; rep < REP_ATTN; ++rep) {
        asm volatile("" ::: "memory");
        const int n   = blockIdx.x;
        const int tid = threadIdx.x;
        const int b = b_ind[n], h = h_ind[n], t = t_ind[n];
        const int eh = b * Ent + h, et = b * Ent + t;
        const int rh = eh * Mm, rt = et * Mm;
        const int hn = mention_num[eh], tn = mention_num[et];

        {
            const int i = tid >> 4, j = tid & 15;
            float v = ch[rh + i] + qt[rt + j]
                    + cqt[rt + i] * bf2f(f_head[(size_t)(rh + i) * Hd + j]);
            if (i >= hn || j >= tn) v = NEGV;
            sm[i][j] = v;
        }
        __syncthreads();

        if (tid < Mm) {
            float m = sm[tid][0];
            #pragma unroll
            for (int jj = 1; jj < Mm; ++jj) m = fmaxf(m, sm[tid][jj]);
            hw[tid] = m;
        } else if (tid < 2 * Mm) {
            const int c = tid - Mm;
            float m = sm[0][c];
            #pragma unroll
            for (int ii = 1; ii < Mm; ++ii) m = fmaxf(m, sm[ii][c]);
            tw[c] = m;
        }
        __syncthreads();

        if (tid == 0) {
            float mx = hw[0];
            #pragma unroll
            for (int ii = 1; ii < Mm; ++ii) mx = fmaxf(mx, hw[ii]);
            float e[Mm]; float s = 0.f;
            #pragma unroll
            for (int ii = 0; ii < Mm; ++ii) { e[ii] = expf(hw[ii] - mx); s += e[ii]; }
            const float inv = 1.f / s;
            #pragma unroll
            for (int ii = 0; ii < Mm; ++ii) hw[ii] = e[ii] * inv;
        } else if (tid == 64) {
            float mx = tw[0];
            #pragma unroll
            for (int ii = 1; ii < Mm; ++ii) mx = fmaxf(mx, tw[ii]);
            float e[Mm]; float s = 0.f;
            #pragma unroll
            for (int ii = 0; ii < Mm; ++ii) { e[ii] = expf(tw[ii] - mx); s += e[ii]; }
            const float inv = 1.f / s;
            #pragma unroll
            for (int ii = 0; ii < Mm; ++ii) tw[ii] = e[ii] * inv;
        }
        __syncthreads();

        const size_t oh = (size_t)n * (2 * Hd);
        const size_t ot = (size_t)(N + n) * (2 * Hd);

        if (tid < 192) {
            const int half = (tid >= 96);
            const int c8 = (tid - half * 96) * 8;
            const float* wgt = half ? tw : hw;
            const unsigned short* fp =
                (half ? f_tail + (size_t)rt * Hd : f_head + (size_t)rh * Hd) + c8;
            float a[8] = {0.f, 0.f, 0.f, 0.f, 0.f, 0.f, 0.f, 0.f};
            #pragma unroll
            for (int ii = 0; ii < Mm; ++ii) {
                u16x8 v = *reinterpret_cast<const u16x8*>(fp + (size_t)ii * Hd);
                const float w = wgt[ii];
                #pragma unroll
                for (int j = 0; j < 8; ++j) a[j] += w * bf2f(v[j]);
            }
            float* dst = out + (half ? ot : oh) + Hd + c8;
            float4 o0 = {a[0], a[1], a[2], a[3]};
            float4 o1 = {a[4], a[5], a[6], a[7]};
            *reinterpret_cast<float4*>(dst)     = o0;
            *reinterpret_cast<float4*>(dst + 4) = o1;
        } else {
            const int q = tid - 192;
            #pragma unroll
            for (int k = q; k < 384; k += 64) {
                const int half = k / 192;
                const int c4 = k - half * 192;
                const float4* src =
                    reinterpret_cast<const float4*>(entity_embed + (size_t)(half ? et : eh) * Hd) + c4;
                float4* dst = reinterpret_cast<float4*>(out + (half ? ot : oh)) + c4;
                *dst = *src;
            }
        }
        __syncthreads();   // hw/tw reads done before next rep overwrites sm
    }
}

// ---------------------------------------------------------------------------
extern "C" void kernel_launch(void* const* d_in, const int* in_sizes, int n_in,
                              void* d_out, int out_size, void* d_ws, size_t ws_size,
                              hipStream_t stream)
{
    const float* entity_embed  = (const float*)d_in[0];
    const float* mention_embed = (const float*)d_in[1];
    const int*   mention_num   = (const int*)d_in[4];
    const int*   b_ind         = (const int*)d_in[5];
    const int*   h_ind         = (const int*)d_in[6];
    const int*   t_ind         = (const int*)d_in[7];
    const float* W_head        = (const float*)d_in[8];
    const float* W_tail        = (const float*)d_in[9];
    const float* w_c           = (const float*)d_in[10];
    const float* w_q           = (const float*)d_in[11];
    const float* w_cq          = (const float*)d_in[12];
    float* out = (float*)d_out;

    const int N = in_sizes[5];            // 4096

    unsigned short* Ab     = (unsigned short*)d_ws;
    unsigned short* Wb     = Ab + (size_t)GM * GK;
    unsigned short* f_head = Wb + (size_t)GN * GK;
    unsigned short* f_tail = f_head + (size_t)GM * Hd;
    float* ch  = (float*)(f_tail + (size_t)GM * Hd);
    float* qt  = ch + GM;
    float* cqt = qt + GM;

    to_bf16<<<(GM + GN) * GK / (8 * 256), 256, 0, stream>>>(
        mention_embed, W_head, W_tail, Ab);

    dim3 gg(GN / 128, GM / 128);          // (12, 21)
    gemm_mfma<<<gg, 256, 0, stream>>>(Ab, Wb, f_head, f_tail);

    row_dots<<<GM / 4, 256, 0, stream>>>(f_head, f_tail, w_c, w_q, w_cq, ch, qt, cqt);

    pair_attn<<<N, 256, 0, stream>>>(f_head, f_tail, ch, qt, cqt,
                                     entity_embed, mention_num,
                                     b_ind, h_ind, t_ind, out, N);
}

// Round 5
// 51.686 us; speedup vs baseline: 9.5332x; 9.5332x over previous
//
#include <hip/hip_runtime.h>
#include <hip/hip_bf16.h>

// Problem constants (from reference)
#define Hd   768
#define Bsz  4
#define Ent  42
#define Mm   16
#define NEGV (-1e9f)

#define GM 2688          // B*E*M rows
#define GN 1536          // concat(head, tail) outputs
#define GK 768
#define NT (GK / 32)     // 24 K-steps

typedef short bf16x8 __attribute__((ext_vector_type(8)));
typedef float f32x4  __attribute__((ext_vector_type(4)));
typedef unsigned short u16x8 __attribute__((ext_vector_type(8)));

static __device__ __forceinline__ unsigned short f2bf(float x) {
    unsigned int u = __float_as_uint(x);
    u += 0x7fffu + ((u >> 16) & 1u);          // RNE
    return (unsigned short)(u >> 16);
}
static __device__ __forceinline__ float bf2f(unsigned short v) {
    return __uint_as_float(((unsigned int)v) << 16);
}

// ---------------------------------------------------------------------------
// Kernel 0: fp32 -> bf16 conversion.  dst rows: [0,2688)=mention_embed,
// [2688,3456)=W_head, [3456,4224)=W_tail.
// ---------------------------------------------------------------------------
__global__ __launch_bounds__(256)
void to_bf16(const float* __restrict__ me, const float* __restrict__ wh,
             const float* __restrict__ wt, unsigned short* __restrict__ dst)
{
    const int t = blockIdx.x * 256 + threadIdx.x;
    const size_t e = (size_t)t * 8;
    const size_t row = e / Hd;                         // 8 | 768 so no straddle
    const float* src;
    size_t off;
    if (row < 2688)      { src = me; off = e; }
    else if (row < 3456) { src = wh; off = e - (size_t)2688 * Hd; }
    else                 { src = wt; off = e - (size_t)3456 * Hd; }
    float4 v0 = *reinterpret_cast<const float4*>(src + off);
    float4 v1 = *reinterpret_cast<const float4*>(src + off + 4);
    u16x8 o;
    o[0] = f2bf(v0.x); o[1] = f2bf(v0.y); o[2] = f2bf(v0.z); o[3] = f2bf(v0.w);
    o[4] = f2bf(v1.x); o[5] = f2bf(v1.y); o[6] = f2bf(v1.z); o[7] = f2bf(v1.w);
    *reinterpret_cast<u16x8*>(dst + e) = o;
}

// ---------------------------------------------------------------------------
// Kernel 1: bf16 MFMA GEMM + ReLU.  64x128 tile (MxN), BK=32, 4 waves, each
// wave owns the full 64-row M and a 32-col N slice: 4x2 16x16x32 frags.
// Grid 504 blocks = 2 blocks/CU = 2 waves/SIMD (vs 1 in round 3).
// Double-buffered LDS, 2-phase prefetch, global_load_lds width=16.
// ---------------------------------------------------------------------------
__global__ __launch_bounds__(256)
void gemm_mfma(const unsigned short* __restrict__ Ab,
               const unsigned short* __restrict__ Wb,
               unsigned short* __restrict__ f_head,
               unsigned short* __restrict__ f_tail)
{
    __shared__ unsigned short As[2][64 * 32];    // 4 KB per buf
    __shared__ unsigned short Bs[2][128 * 32];   // 8 KB per buf

    const int tid  = threadIdx.x;
    const int wave = tid >> 6;
    const int lane = tid & 63;
    const int n0 = blockIdx.x * 128;
    const int m0 = blockIdx.y * 64;

    // staging: each wave stages 16 rows (1 KB); lane l -> +l*16B linear
    const int srow = wave * 16 + (lane >> 2);          // 0..63
    const int scol = (lane & 3) * 8;                   // elements
    const unsigned short* Aga = Ab + (size_t)(m0 + srow) * GK + scol;
    const unsigned short* Bga = Wb + (size_t)(n0 + srow) * GK + scol;

#define STAGE(buf, k0) do { \
    __builtin_amdgcn_global_load_lds((const __attribute__((address_space(1))) void*)(Aga + (k0)), \
        (__attribute__((address_space(3))) void*)(As[buf] + wave * 512), 16, 0, 0); \
    __builtin_amdgcn_global_load_lds((const __attribute__((address_space(1))) void*)(Bga + (k0)), \
        (__attribute__((address_space(3))) void*)(Bs[buf] + wave * 512), 16, 0, 0); \
    __builtin_amdgcn_global_load_lds((const __attribute__((address_space(1))) void*)(Bga + 64 * GK + (k0)), \
        (__attribute__((address_space(3))) void*)(Bs[buf] + 2048 + wave * 512), 16, 0, 0); \
} while (0)

    const int frow = lane & 15;
    const int koff = (lane >> 4) * 8;

    f32x4 acc[4][2];
    {
        f32x4 z = {0.f, 0.f, 0.f, 0.f};
        #pragma unroll
        for (int mi = 0; mi < 4; ++mi) { acc[mi][0] = z; acc[mi][1] = z; }
    }

    STAGE(0, 0);
    int cur = 0;
    #pragma unroll 1
    for (int t = 0; t < NT; ++t) {
        __syncthreads();                 // drains vmcnt: buf[cur] ready; prev reads done
        if (t < NT - 1) STAGE(cur ^ 1, (t + 1) * 32);
        const unsigned short* ap = As[cur] + frow * 32 + koff;
        const unsigned short* bp = Bs[cur] + (wave * 32 + frow) * 32 + koff;
        bf16x8 a[4], b[2];
        #pragma unroll
        for (int mi = 0; mi < 4; ++mi)
            a[mi] = *reinterpret_cast<const bf16x8*>(ap + mi * 16 * 32);
        b[0] = *reinterpret_cast<const bf16x8*>(bp);
        b[1] = *reinterpret_cast<const bf16x8*>(bp + 16 * 32);
        #pragma unroll
        for (int mi = 0; mi < 4; ++mi) {
            acc[mi][0] = __builtin_amdgcn_mfma_f32_16x16x32_bf16(a[mi], b[0], acc[mi][0], 0, 0, 0);
            acc[mi][1] = __builtin_amdgcn_mfma_f32_16x16x32_bf16(a[mi], b[1], acc[mi][1], 0, 0, 0);
        }
        cur ^= 1;
    }
#undef STAGE

    // C/D layout (m89-verified): col = lane&15, row = (lane>>4)*4 + reg.
    // N-tile 128 | 768, so each block is entirely head or tail.
    const bool isHead = (n0 < Hd);
    unsigned short* outp = isHead ? f_head : f_tail;
    const int nbase = (isHead ? n0 : (n0 - Hd)) + wave * 32 + frow;
    const int rbase = m0 + (lane >> 4) * 4;
    #pragma unroll
    for (int mi = 0; mi < 4; ++mi)
        #pragma unroll
        for (int ni = 0; ni < 2; ++ni)
            #pragma unroll
            for (int j = 0; j < 4; ++j) {
                float v = fmaxf(acc[mi][ni][j], 0.f);
                outp[(size_t)(rbase + mi * 16 + j) * Hd + nbase + ni * 16] = f2bf(v);
            }
}

// ---------------------------------------------------------------------------
// Kernel 2: per-row dots. One wave per row, shuffle reduce.
// ---------------------------------------------------------------------------
__global__ __launch_bounds__(256)
void row_dots(const unsigned short* __restrict__ f_head,
              const unsigned short* __restrict__ f_tail,
              const float* __restrict__ w_c, const float* __restrict__ w_q,
              const float* __restrict__ w_cq,
              float* __restrict__ ch, float* __restrict__ qt, float* __restrict__ cqt)
{
    const int wave = threadIdx.x >> 6;
    const int lane = threadIdx.x & 63;
    const int r = blockIdx.x * 4 + wave;
    const unsigned short* fh = f_head + (size_t)r * Hd;
    const unsigned short* ft = f_tail + (size_t)r * Hd;
    float pc = 0.f, pq = 0.f, pcq = 0.f;
    #pragma unroll
    for (int j = 0; j < Hd / 64; ++j) {
        const int c = j * 64 + lane;
        float vh = bf2f(fh[c]), vt = bf2f(ft[c]);
        pc += vh * w_c[c]; pq += vt * w_q[c]; pcq += vt * w_cq[c];
    }
    #pragma unroll
    for (int s = 32; s >= 1; s >>= 1) {
        pc  += __shfl_down(pc, s);
        pq  += __shfl_down(pq, s);
        pcq += __shfl_down(pcq, s);
    }
    if (lane == 0) { ch[r] = pc; qt[r] = pq; cqt[r] = pcq; }
}

// ---------------------------------------------------------------------------
// Kernel 3: per-pair 16x16 score, dual softmax, weighted pooling, concat out.
// Pooling loops only over rows with NONZERO weight: rows >= mention_num are
// fully masked -> softmax weight underflows to exactly 0.0f, so bounding the
// loop at hn/tn is bit-exact and halves the gather traffic on average.
// ---------------------------------------------------------------------------
__global__ __launch_bounds__(256)
void pair_attn(const unsigned short* __restrict__ f_head,
               const unsigned short* __restrict__ f_tail,
               const float* __restrict__ ch, const float* __restrict__ qt,
               const float* __restrict__ cqt,
               const float* __restrict__ entity_embed,
               const int* __restrict__ mention_num,
               const int* __restrict__ b_ind, const int* __restrict__ h_ind,
               const int* __restrict__ t_ind,
               float* __restrict__ out, int N)
{
    const int n   = blockIdx.x;
    const int tid = threadIdx.x;
    const int b = b_ind[n], h = h_ind[n], t = t_ind[n];
    const int eh = b * Ent + h, et = b * Ent + t;
    const int rh = eh * Mm, rt = et * Mm;
    const int hn = mention_num[eh], tn = mention_num[et];

    __shared__ float sm[Mm][Mm];
    __shared__ float hw[Mm], tw[Mm];

    {
        const int i = tid >> 4, j = tid & 15;
        float v;
        if (i < hn && j < tn)
            v = ch[rh + i] + qt[rt + j]
              + cqt[rt + i] * bf2f(f_head[(size_t)(rh + i) * Hd + j]);
        else
            v = NEGV;
        sm[i][j] = v;
    }
    __syncthreads();

    if (tid < Mm) {                 // row max (over j) -> hw
        float m = sm[tid][0];
        #pragma unroll
        for (int jj = 1; jj < Mm; ++jj) m = fmaxf(m, sm[tid][jj]);
        hw[tid] = m;
    } else if (tid < 2 * Mm) {      // col max (over i) -> tw
        const int c = tid - Mm;
        float m = sm[0][c];
        #pragma unroll
        for (int ii = 1; ii < Mm; ++ii) m = fmaxf(m, sm[ii][c]);
        tw[c] = m;
    }
    __syncthreads();

    if (tid == 0) {
        float mx = hw[0];
        #pragma unroll
        for (int ii = 1; ii < Mm; ++ii) mx = fmaxf(mx, hw[ii]);
        float e[Mm]; float s = 0.f;
        #pragma unroll
        for (int ii = 0; ii < Mm; ++ii) { e[ii] = expf(hw[ii] - mx); s += e[ii]; }
        const float inv = 1.f / s;
        #pragma unroll
        for (int ii = 0; ii < Mm; ++ii) hw[ii] = e[ii] * inv;
    } else if (tid == 64) {
        float mx = tw[0];
        #pragma unroll
        for (int ii = 1; ii < Mm; ++ii) mx = fmaxf(mx, tw[ii]);
        float e[Mm]; float s = 0.f;
        #pragma unroll
        for (int ii = 0; ii < Mm; ++ii) { e[ii] = expf(tw[ii] - mx); s += e[ii]; }
        const float inv = 1.f / s;
        #pragma unroll
        for (int ii = 0; ii < Mm; ++ii) tw[ii] = e[ii] * inv;
    }
    __syncthreads();

    const size_t oh = (size_t)n * (2 * Hd);
    const size_t ot = (size_t)(N + n) * (2 * Hd);

    if (tid < 192) {
        // weighted pooling: 96 threads/half, 8 consecutive cols each.
        // Rows >= cnt have weight exactly 0 -> skip their loads entirely.
        const int half = (tid >= 96);
        const int c8 = (tid - half * 96) * 8;
        const int cnt = half ? tn : hn;
        const float* wgt = half ? tw : hw;
        const unsigned short* fp =
            (half ? f_tail + (size_t)rt * Hd : f_head + (size_t)rh * Hd) + c8;
        float a[8] = {0.f, 0.f, 0.f, 0.f, 0.f, 0.f, 0.f, 0.f};
        for (int ii = 0; ii < cnt; ++ii) {
            u16x8 v = *reinterpret_cast<const u16x8*>(fp + (size_t)ii * Hd);
            const float w = wgt[ii];
            #pragma unroll
            for (int j = 0; j < 8; ++j) a[j] += w * bf2f(v[j]);
        }
        float* dst = out + (half ? ot : oh) + Hd + c8;
        float4 o0 = {a[0], a[1], a[2], a[3]};
        float4 o1 = {a[4], a[5], a[6], a[7]};
        *reinterpret_cast<float4*>(dst)     = o0;
        *reinterpret_cast<float4*>(dst + 4) = o1;
    } else {
        // 64 threads copy 2x768 f32 entity embeds = 384 float4, 6 each
        const int q = tid - 192;
        #pragma unroll
        for (int k = q; k < 384; k += 64) {
            const int half = k / 192;
            const int c4 = k - half * 192;
            const float4* src =
                reinterpret_cast<const float4*>(entity_embed + (size_t)(half ? et : eh) * Hd) + c4;
            float4* dst = reinterpret_cast<float4*>(out + (half ? ot : oh)) + c4;
            *dst = *src;
        }
    }
}

// ---------------------------------------------------------------------------
extern "C" void kernel_launch(void* const* d_in, const int* in_sizes, int n_in,
                              void* d_out, int out_size, void* d_ws, size_t ws_size,
                              hipStream_t stream)
{
    const float* entity_embed  = (const float*)d_in[0];
    const float* mention_embed = (const float*)d_in[1];
    // d_in[2] sent_embed, d_in[3] entity_info: unused by reference
    const int*   mention_num   = (const int*)d_in[4];
    const int*   b_ind         = (const int*)d_in[5];
    const int*   h_ind         = (const int*)d_in[6];
    const int*   t_ind         = (const int*)d_in[7];
    const float* W_head        = (const float*)d_in[8];
    const float* W_tail        = (const float*)d_in[9];
    const float* w_c           = (const float*)d_in[10];
    const float* w_q           = (const float*)d_in[11];
    const float* w_cq          = (const float*)d_in[12];
    float* out = (float*)d_out;

    const int N = in_sizes[5];            // 4096

    // workspace layout (bf16 activations): total ~14.8 MiB
    unsigned short* Ab     = (unsigned short*)d_ws;          // [2688*768]
    unsigned short* Wb     = Ab + (size_t)GM * GK;           // [1536*768] (head||tail)
    unsigned short* f_head = Wb + (size_t)GN * GK;           // [2688*768]
    unsigned short* f_tail = f_head + (size_t)GM * Hd;       // [2688*768]
    float* ch  = (float*)(f_tail + (size_t)GM * Hd);
    float* qt  = ch + GM;
    float* cqt = qt + GM;

    // 0) convert inputs to bf16 (Ab and Wb contiguous -> one kernel)
    to_bf16<<<(GM + GN) * GK / (8 * 256), 256, 0, stream>>>(
        mention_embed, W_head, W_tail, Ab);

    // 1) fused projection GEMM + ReLU -> bf16 f_head / f_tail
    dim3 gg(GN / 128, GM / 64);           // (12, 42) = 504 blocks
    gemm_mfma<<<gg, 256, 0, stream>>>(Ab, Wb, f_head, f_tail);

    // 2) per-row dots
    row_dots<<<GM / 4, 256, 0, stream>>>(f_head, f_tail, w_c, w_q, w_cq, ch, qt, cqt);

    // 3) per-pair attention + output
    pair_attn<<<N, 256, 0, stream>>>(f_head, f_tail, ch, qt, cqt,
                                     entity_embed, mention_num,
                                     b_ind, h_ind, t_ind, out, N);
}